// Round 2
// baseline (391.718 us; speedup 1.0000x reference)
//
#include <hip/hip_runtime.h>
#include <stdint.h>
#include <stddef.h>

#define B_  16
#define U_  512
#define LX_ 1024
#define LY_ 1024
#define H_  8
#define D_  64

typedef unsigned short ushort_t;
typedef unsigned int   uint_t;
typedef __bf16 v8bf  __attribute__((ext_vector_type(8)));
typedef float  v16f  __attribute__((ext_vector_type(16)));

__device__ __forceinline__ ushort_t bf16u(float f) {
    uint_t u = __float_as_uint(f);
    uint_t r = (u + 0x7FFFu + ((u >> 16) & 1u)) >> 16;
    return (ushort_t)r;
}
__device__ __forceinline__ float bfu2f(ushort_t u) {
    return __uint_as_float(((uint_t)u) << 16);
}
// RNE-pack two fp32 -> packed bf16x2 (low=f0) using v_perm_b32.
__device__ __forceinline__ uint_t pkbf16(float f0, float f1) {
    uint_t u0 = __float_as_uint(f0), u1 = __float_as_uint(f1);
    u0 = u0 + 0x7FFFu + ((u0 >> 16) & 1u);
    u1 = u1 + 0x7FFFu + ((u1 >> 16) & 1u);
    return __builtin_amdgcn_perm(u1, u0, 0x07060302u);
}
// async global->LDS, 16B/lane. LDS dest is wave-uniform base + lane*16, so
// swizzling must be applied to the GLOBAL source chunk, not the LDS address.
__device__ __forceinline__ void gload16(const void* g, void* l) {
    auto gp = (const __attribute__((address_space(1))) uint32_t*)(uintptr_t)g;
    auto lp = (__attribute__((address_space(3))) uint32_t*)(uintptr_t)l;
    __builtin_amdgcn_global_load_lds(gp, lp, 16, 0, 0);
}

// ---------------------------------------------------------------------------
// Detect mask element width: int32 (all first-1024 words <= 1) vs uint8.
// ---------------------------------------------------------------------------
__global__ void detect_kernel(const uint_t* __restrict__ mask, int* __restrict__ flag) {
    __shared__ int s;
    if (threadIdx.x == 0) s = 0;
    __syncthreads();
    int c = 0;
    for (int i = threadIdx.x; i < 1024; i += 256) c += (mask[i] <= 1u) ? 1 : 0;
    atomicAdd(&s, c);
    __syncthreads();
    if (threadIdx.x == 0) *flag = (s >= 1000) ? 1 : 0;
}

// ---------------------------------------------------------------------------
// Single mask pass: maskBits (ballot) + n_el (popcount). One wave per row.
// ---------------------------------------------------------------------------
__global__ __launch_bounds__(256) void nelmask_kernel(const void* __restrict__ mask,
                                                      const int* __restrict__ flag,
                                                      float* __restrict__ nel,
                                                      uint_t* __restrict__ mb) {
    int row  = blockIdx.x * 4 + (threadIdx.x >> 6);   // b*1024 + x
    int lane = threadIdx.x & 63;
    const int isInt = *flag;
    const uint8_t* m8  = (const uint8_t*)mask + (size_t)row * LY_;
    const int*     m32 = (const int*)mask + (size_t)row * LY_;
    int cnt = 0;
    for (int yg = 0; yg < LY_ / 64; ++yg) {
        int y = yg * 64 + lane;
        bool p = isInt ? (m32[y] != 0) : (m8[y] != 0);
        unsigned long long bal = __ballot(p);
        if (lane == 0) {
            mb[(size_t)row * 32 + yg * 2]     = (uint_t)bal;
            mb[(size_t)row * 32 + yg * 2 + 1] = (uint_t)(bal >> 32);
            cnt += __popcll(bal);
        }
    }
    if (lane == 0) nel[row] = (float)(cnt > 0 ? cnt : 1);
}

// ---------------------------------------------------------------------------
// All three 512x512 weights -> bf16 in one dispatch (blockIdx.y selects).
// ---------------------------------------------------------------------------
__global__ __launch_bounds__(256) void castw_kernel(const float* __restrict__ w0,
                                                    const float* __restrict__ w1,
                                                    const float* __restrict__ w2,
                                                    ushort_t* __restrict__ o0,
                                                    ushort_t* __restrict__ o1,
                                                    ushort_t* __restrict__ o2) {
    const float* s = blockIdx.y == 0 ? w0 : (blockIdx.y == 1 ? w1 : w2);
    ushort_t*    d = blockIdx.y == 0 ? o0 : (blockIdx.y == 1 ? o1 : o2);
    int i = (blockIdx.x * 256 + threadIdx.x) * 4;
    float4 v = *(const float4*)&s[i];
    ushort4 p;
    p.x = bf16u(v.x); p.y = bf16u(v.y); p.z = bf16u(v.z); p.w = bf16u(v.w);
    *(ushort4*)&d[i] = p;
}

// ---------------------------------------------------------------------------
// x and y [b][u][l] fp32 -> [b][l][u] bf16, 64x64 LDS tiles. z = b + 16*sel.
// ---------------------------------------------------------------------------
__global__ __launch_bounds__(256) void castT_kernel(const float* __restrict__ X,
                                                    const float* __restrict__ Y,
                                                    ushort_t* __restrict__ XT,
                                                    ushort_t* __restrict__ YT) {
    const int l0 = blockIdx.x * 64;
    const int u0 = blockIdx.y * 64;
    const int b  = blockIdx.z & 15;
    const int sel = blockIdx.z >> 4;
    const float* S = sel ? Y : X;
    ushort_t*  Dst = sel ? YT : XT;
    __shared__ ushort_t T[64][72];
    const int tid = threadIdx.x;
    #pragma unroll
    for (int e = 0; e < 4; ++e) {
        int ci = e * 256 + tid;            // 0..1023 float4s
        int r = ci >> 4, c4 = (ci & 15) * 4;
        float4 v = *(const float4*)&S[((size_t)(b * U_ + u0 + r) << 10) + l0 + c4];
        T[r][c4 + 0] = bf16u(v.x); T[r][c4 + 1] = bf16u(v.y);
        T[r][c4 + 2] = bf16u(v.z); T[r][c4 + 3] = bf16u(v.w);
    }
    __syncthreads();
    #pragma unroll
    for (int e = 0; e < 2; ++e) {
        int ci = e * 256 + tid;            // 0..511 chunks of 8
        int lr = ci >> 3, cc = ci & 7;
        ushort_t tmp[8];
        #pragma unroll
        for (int j = 0; j < 8; ++j) tmp[j] = T[cc * 8 + j][lr];
        *(uint4*)&Dst[((size_t)((b << 10) + l0 + lr)) * U_ + u0 + cc * 8] = *(uint4*)tmp;
    }
}

// ---------------------------------------------------------------------------
// Generalized bf16 MFMA GEMM: Out[b][m][n] = sum_k A_b[m][k] * B_b[n][k]
// K = 512 (= lda = ldb). 128x128 tile, BK=64, gload16 staging, src-xor swizzle.
// aStr/bStr: per-batch element strides (0 = shared). Out: oStr*b + m*ldOut + n.
// ---------------------------------------------------------------------------
template <int OUTF32>
__global__ __launch_bounds__(256) void gemm_mfma(const ushort_t* __restrict__ A, size_t aStr,
                                                 const ushort_t* __restrict__ Bm, size_t bStr,
                                                 void* __restrict__ Out, size_t oStr, int ldOut) {
    const int n0 = blockIdx.x * 128;
    const int m0 = blockIdx.y * 128;
    const int b  = blockIdx.z;
    __shared__ __align__(16) ushort_t As[128 * 64];
    __shared__ __align__(16) ushort_t Bs[128 * 64];
    const int tid = threadIdx.x;
    const ushort_t* Ab = A + aStr * b;
    const ushort_t* Bb = Bm + bStr * b;

    const int w = tid >> 6, lane = tid & 63, lo = lane & 31, hi = lane >> 5;
    const int wm = (w >> 1) * 64, wn = (w & 1) * 64;

    v16f acc00, acc01, acc10, acc11;
    #pragma unroll
    for (int i = 0; i < 16; ++i) { acc00[i] = 0.f; acc01[i] = 0.f; acc10[i] = 0.f; acc11[i] = 0.f; }

    for (int kk = 0; kk < 8; ++kk) {
        const int k0 = kk * 64;
        #pragma unroll
        for (int e = 0; e < 4; ++e) {
            int ci = e * 256 + tid;          // 0..1023 16B chunks
            int r = ci >> 3, c = ci & 7;
            int g = (c ^ (r & 7)) << 3;      // swizzle on SOURCE chunk
            gload16(&Ab[(size_t)(m0 + r) * U_ + k0 + g], &As[ci * 8]);
            gload16(&Bb[(size_t)(n0 + r) * U_ + k0 + g], &Bs[ci * 8]);
        }
        __syncthreads();
        #pragma unroll
        for (int ks = 0; ks < 4; ++ks) {
            int ch = ks * 2 + hi;
            int rA0 = wm + lo, rA1 = wm + 32 + lo;
            int rB0 = wn + lo, rB1 = wn + 32 + lo;
            v8bf a0 = *(v8bf*)&As[rA0 * 64 + ((ch ^ (rA0 & 7)) << 3)];
            v8bf a1 = *(v8bf*)&As[rA1 * 64 + ((ch ^ (rA1 & 7)) << 3)];
            v8bf b0 = *(v8bf*)&Bs[rB0 * 64 + ((ch ^ (rB0 & 7)) << 3)];
            v8bf b1 = *(v8bf*)&Bs[rB1 * 64 + ((ch ^ (rB1 & 7)) << 3)];
            acc00 = __builtin_amdgcn_mfma_f32_32x32x16_bf16(a0, b0, acc00, 0, 0, 0);
            acc01 = __builtin_amdgcn_mfma_f32_32x32x16_bf16(a0, b1, acc01, 0, 0, 0);
            acc10 = __builtin_amdgcn_mfma_f32_32x32x16_bf16(a1, b0, acc10, 0, 0, 0);
            acc11 = __builtin_amdgcn_mfma_f32_32x32x16_bf16(a1, b1, acc11, 0, 0, 0);
        }
        __syncthreads();
    }

    #pragma unroll
    for (int mi = 0; mi < 2; ++mi) {
        #pragma unroll
        for (int nj = 0; nj < 2; ++nj) {
            v16f c = mi ? (nj ? acc11 : acc10) : (nj ? acc01 : acc00);
            int n = n0 + wn + nj * 32 + lo;
            #pragma unroll
            for (int r = 0; r < 16; ++r) {
                int m = m0 + wm + mi * 32 + (r & 3) + 8 * (r >> 2) + 4 * hi;
                size_t addr = oStr * b + (size_t)m * ldOut + n;
                if (OUTF32) ((float*)Out)[addr] = c[r];
                else        ((ushort_t*)Out)[addr] = bf16u(c[r]);
            }
        }
    }
}

// ---------------------------------------------------------------------------
// Ka[b][u=h*64+d][y] bf16 -> Kb[b][h][y][d] bf16 (64x64 LDS transpose)
// ---------------------------------------------------------------------------
__global__ __launch_bounds__(256) void ktranspose_kernel(const ushort_t* __restrict__ Ka,
                                                         ushort_t* __restrict__ Kb) {
    const int y0 = blockIdx.x * 64;
    const int h  = blockIdx.y;
    const int b  = blockIdx.z;
    __shared__ ushort_t T[64][72];
    const int tid = threadIdx.x;

    #pragma unroll
    for (int e = 0; e < 2; ++e) {
        int idx = e * 256 + tid;
        int d = idx >> 3, c = idx & 7;
        uint4 v = *(const uint4*)&Ka[((size_t)(b * U_ + h * D_ + d) << 10) + y0 + c * 8];
        *(uint4*)&T[d][c * 8] = v;
    }
    __syncthreads();
    #pragma unroll
    for (int e = 0; e < 2; ++e) {
        int idx = e * 256 + tid;
        int yy = idx >> 3, dc = idx & 7;
        ushort_t tmp[8];
        #pragma unroll
        for (int j = 0; j < 8; ++j) tmp[j] = T[dc * 8 + j][yy];
        *(uint4*)&Kb[(((size_t)(b * H_ + h) << 10) + y0 + yy) * D_ + dc * 8] = *(uint4*)tmp;
    }
}

// ---------------------------------------------------------------------------
// Fused bf16-MFMA attention, in-register S->C handoff, 32 KB LDS.
//
// LDS is ONLY the double-buffered K tiles (KB dbuf 16KB | KA dbuf 16KB), so
// all 1024 blocks are co-resident at 4 blocks/CU (16 waves/CU, single
// dispatch phase -- no occupancy tail).  Q never touches LDS: the S-phase
// B-fragments are loaded straight from global (QT is L2/L3-resident), and
// the epilogue re-reads its 8B of Q per lane from global.  After the y-loop
// the K region is reused as the f32 cross-wave reduction buffer (32KB) and
// then as the bf16 Et staging buffer (16KB); E is carried across that
// overlay in 16 VGPRs.
// ---------------------------------------------------------------------------
typedef uint_t v2u __attribute__((ext_vector_type(2)));

// s: 16 f32 of one 32x32 S^T block (D-layout). wbh: mask word >> (hi*8).
// fr[t]: B-operand v8bf fragment for k-step t (t=0: y_off 0..15, t=1: 16..31).
__device__ __forceinline__ void conv_sblock(const v16f& s, uint_t wbh, v8bf* fr) {
    uint_t pk[8];
    #pragma unroll
    for (int i = 0; i < 8; ++i) {
        float f0 = fmaxf(s[2 * i + 0], 0.f);
        float f1 = fmaxf(s[2 * i + 1], 0.f);
        uint_t r;
        asm("v_cvt_pk_bf16_f32 %0, %1, %2" : "=v"(r) : "v"(f0), "v"(f1));
        pk[i] = r;
    }
    #pragma unroll
    for (int t = 0; t < 2; ++t) {
        // swap(A,B): A'[32+i]=B[i], B'[i]=A[32+i]  (exchange hi-half of A with lo-half of B)
        auto ra = __builtin_amdgcn_permlane32_swap(pk[4 * t + 0], pk[4 * t + 2], false, false);
        auto rb = __builtin_amdgcn_permlane32_swap(pk[4 * t + 1], pk[4 * t + 3], false, false);
        uint_t w0 = ra[0];   // j={0,1}:  y_off = t*16 + hi*8 + {0,1}
        uint_t w1 = rb[0];   // j={2,3}
        uint_t w2 = ra[1];   // j={4,5}
        uint_t w3 = rb[1];   // j={6,7}
        uint_t u0 = wbh >> (t * 16 + 0);
        uint_t u1 = wbh >> (t * 16 + 2);
        uint_t u2 = wbh >> (t * 16 + 4);
        uint_t u3 = wbh >> (t * 16 + 6);
        w0 &= ((u0 & 1u) * 0xFFFFu) | ((u0 & 2u) * 0x7FFF8000u);
        w1 &= ((u1 & 1u) * 0xFFFFu) | ((u1 & 2u) * 0x7FFF8000u);
        w2 &= ((u2 & 1u) * 0xFFFFu) | ((u2 & 2u) * 0x7FFF8000u);
        w3 &= ((u3 & 1u) * 0xFFFFu) | ((u3 & 2u) * 0x7FFF8000u);
        union { uint_t u[4]; v8bf b; } cv;
        cv.u[0] = w0; cv.u[1] = w1; cv.u[2] = w2; cv.u[3] = w3;
        fr[t] = cv.b;
    }
}

__global__ __launch_bounds__(256, 4) void attn_mfma(const ushort_t* __restrict__ QTg,
                                                    const ushort_t* __restrict__ Ka_g,
                                                    const ushort_t* __restrict__ Kb_g,
                                                    const uint_t* __restrict__ mbits,
                                                    const float* __restrict__ nel,
                                                    ushort_t* __restrict__ ETg) {
    const int tid = threadIdx.x;
    const int id  = blockIdx.x;
    const int bh  = id & 127;          // same-bh blocks -> same XCD (id%8 heuristic)
    const int x0g = (id >> 7) * 128;
    const int b = bh >> 3, h = bh & 7;

    // 32 KB: KB dbuf [0,16KB) | KA dbuf [16KB,32KB).  Reused post-loop.
    __shared__ __align__(16) ushort_t SM[4 * 4096];

    const int w    = tid >> 6;
    const int lane = tid & 63;
    const int lo   = lane & 31;
    const int hi   = lane >> 5;
    const int yw   = w & 1;            // y-half this wave's S covers
    const int xws  = (w >> 1) * 64;    // x-half base

    const ushort_t* KaBase = Ka_g + ((size_t)(b * U_ + h * D_)) * LY_;
    const ushort_t* KbBase = Kb_g + ((size_t)(b * H_ + h)) * LY_ * D_;
    const int bx = b * LX_ + x0g;

    // ---- stage first K tile into buffer 0 ----
    #pragma unroll
    for (int e = 0; e < 2; ++e) {
        int ci = e * 256 + tid;
        int r = ci >> 3, c = ci & 7;
        int g8 = (c ^ (r & 7)) << 3;
        gload16(&KbBase[(size_t)r * D_ + g8], &SM[ci * 8]);
        gload16(&KaBase[(size_t)r * LY_ + g8], &SM[8192 + ci * 8]);
    }

    // ---- Q B-fragments straight from global (loop-invariant, 32 VGPR) ----
    v8bf qf0[4], qf1[4];
    {
        const ushort_t* q0 = QTg + (size_t)(bx + xws + lo) * U_ + h * D_;
        const ushort_t* q1 = q0 + (size_t)32 * U_;
        #pragma unroll
        for (int kt = 0; kt < 4; ++kt) {
            int ch = kt * 2 + hi;
            qf0[kt] = *(const v8bf*)&q0[ch * 8];
            qf1[kt] = *(const v8bf*)&q1[ch * 8];
        }
    }

    // partial-C accumulators: [d-half][x-half], y summed only over this yw-half
    v16f acc00, acc01, acc10, acc11;
    #pragma unroll
    for (int i = 0; i < 16; ++i) { acc00[i] = 0.f; acc01[i] = 0.f; acc10[i] = 0.f; acc11[i] = 0.f; }

    const int rowA = yw * 32 + lo;

    __syncthreads();   // first tile staged (drains gload_lds)

    for (int tt = 0; tt < 16; ++tt) {
        const int y0 = tt * 64;
        ushort_t* KBc = SM + (tt & 1) * 4096;
        ushort_t* KAc = SM + 8192 + (tt & 1) * 4096;

        // prefetch next tile into other buffer; drained by end-of-tile barrier
        if (tt < 15) {
            ushort_t* KBn = SM + ((tt + 1) & 1) * 4096;
            ushort_t* KAn = SM + 8192 + ((tt + 1) & 1) * 4096;
            const int yn = y0 + 64;
            #pragma unroll
            for (int e = 0; e < 2; ++e) {
                int ci = e * 256 + tid;
                int r = ci >> 3, c = ci & 7;
                int g8 = (c ^ (r & 7)) << 3;
                gload16(&KbBase[(size_t)(yn + r) * D_ + g8], &KBn[ci * 8]);
                gload16(&KaBase[(size_t)r * LY_ + yn + g8], &KAn[ci * 8]);
            }
        }
        uint_t wb0 = mbits[((size_t)(bx + xws + lo)) * 32 + (y0 >> 5) + yw];
        uint_t wb1 = mbits[((size_t)(bx + xws + 32 + lo)) * 32 + (y0 >> 5) + yw];

        // ---- S-phase: S^T = Kb * Qt^T (B-frags from registers) ----
        v16f s0, s1;
        #pragma unroll
        for (int i = 0; i < 16; ++i) { s0[i] = 0.f; s1[i] = 0.f; }
        #pragma unroll
        for (int kt = 0; kt < 4; ++kt) {
            int ch = kt * 2 + hi;
            v8bf a = *(v8bf*)&KBc[rowA * 64 + ((ch ^ (rowA & 7)) << 3)];
            s0 = __builtin_amdgcn_mfma_f32_32x32x16_bf16(a, qf0[kt], s0, 0, 0, 0);
            s1 = __builtin_amdgcn_mfma_f32_32x32x16_bf16(a, qf1[kt], s1, 0, 0, 0);
        }

        // ---- relu + mask + pack + permlane redistribute (all in-register) ----
        v8bf fr0[2], fr1[2];
        conv_sblock(s0, wb0 >> (hi * 8), fr0);
        conv_sblock(s1, wb1 >> (hi * 8), fr1);

        // ---- C-phase: partial C[d][x] += Ka * S (k = this wave's 32 y's) ----
        #pragma unroll
        for (int t2 = 0; t2 < 2; ++t2) {
            int ch = yw * 4 + t2 * 2 + hi;
            v8bf a0 = *(v8bf*)&KAc[lo * 64 + ((ch ^ (lo & 7)) << 3)];
            v8bf a1 = *(v8bf*)&KAc[(32 + lo) * 64 + ((ch ^ ((32 + lo) & 7)) << 3)];
            acc00 = __builtin_amdgcn_mfma_f32_32x32x16_bf16(a0, fr0[t2], acc00, 0, 0, 0);
            acc01 = __builtin_amdgcn_mfma_f32_32x32x16_bf16(a0, fr1[t2], acc01, 0, 0, 0);
            acc10 = __builtin_amdgcn_mfma_f32_32x32x16_bf16(a1, fr0[t2], acc10, 0, 0, 0);
            acc11 = __builtin_amdgcn_mfma_f32_32x32x16_bf16(a1, fr1[t2], acc11, 0, 0, 0);
        }
        __syncthreads();   // drains prefetch vmcnt + protects buffer swap
    }

    // ---- cross-wave pairwise C reduction through dead K-buffer space ----
    // region layout (f32): pair*4096 + {0: dh0 partial written by yw1,
    //                                  2048: dh1 partial written by yw0}
    float* red = (float*)SM;
    const int pair = w >> 1;
    {
        float* wr = red + pair * 4096 + (1 - yw) * 2048;
        #pragma unroll
        for (int xh = 0; xh < 2; ++xh) {
            const v16f& c = (yw == 1) ? (xh ? acc01 : acc00) : (xh ? acc11 : acc10);
            int xl2 = xh * 32 + lo;
            #pragma unroll
            for (int q = 0; q < 4; ++q) {
                int chunk = (q * 2 + hi) ^ (xl2 & 7);   // 16B-chunk xor-swizzle
                float4 v = make_float4(c[q * 4 + 0], c[q * 4 + 1], c[q * 4 + 2], c[q * 4 + 3]);
                *(float4*)&wr[xl2 * 32 + chunk * 4] = v;
            }
        }
    }
    __syncthreads();
    // ---- E = 0.5*Q + C*(0.0625/nel): Q re-read from global; E held in regs ----
    uint2 ebuf[2][4];
    {
        const int dh = yw;                       // this wave finalizes d-half = yw
        const float* rd = red + pair * 4096 + yw * 2048;
        #pragma unroll
        for (int xh = 0; xh < 2; ++xh) {
            const v16f& c = (dh == 0) ? (xh ? acc01 : acc00) : (xh ? acc11 : acc10);
            int xl2 = xh * 32 + lo;
            int xl  = xws + xl2;
            float invn = 0.0625f / nel[bx + xl];
            const ushort_t* qg = QTg + (size_t)(bx + xl) * U_ + h * D_ + dh * 32 + 4 * hi;
            #pragma unroll
            for (int q = 0; q < 4; ++q) {
                int chunk = (q * 2 + hi) ^ (xl2 & 7);
                float4 v = *(const float4*)&rd[xl2 * 32 + chunk * 4];
                ushort_t q4[4];
                *(uint2*)q4 = *(const uint2*)&qg[q * 8];
                ushort_t e4[4];
                e4[0] = bf16u(0.5f * bfu2f(q4[0]) + (c[q * 4 + 0] + v.x) * invn);
                e4[1] = bf16u(0.5f * bfu2f(q4[1]) + (c[q * 4 + 1] + v.y) * invn);
                e4[2] = bf16u(0.5f * bfu2f(q4[2]) + (c[q * 4 + 2] + v.z) * invn);
                e4[3] = bf16u(0.5f * bfu2f(q4[3]) + (c[q * 4 + 3] + v.w) * invn);
                ebuf[xh][q] = *(uint2*)e4;
            }
        }
    }
    __syncthreads();   // reduction reads done; region becomes Et staging
    {
        ushort_t* Et = SM;
        const int dh = yw;
        #pragma unroll
        for (int xh = 0; xh < 2; ++xh) {
            int xl = xws + xh * 32 + lo;
            #pragma unroll
            for (int q = 0; q < 4; ++q) {
                int d0 = dh * 32 + q * 8 + 4 * hi;                 // d0&7 == 4*hi
                int base = xl * 64 + ((((d0 >> 3) ^ (xl & 7)) << 3) | (4 * hi));
                *(uint2*)&Et[base] = ebuf[xh][q];
            }
        }
    }
    __syncthreads();
    // ---- write ET[b][x][h*64+d] coalesced (un-swizzle on read) ----
    #pragma unroll
    for (int e = 0; e < 4; ++e) {
        int idx = e * 256 + tid;
        int row = idx >> 3, cc = idx & 7;
        uint4 v = *(const uint4*)&SM[row * 64 + ((cc ^ (row & 7)) << 3)];
        *(uint4*)&ETg[((size_t)(bx + row)) * U_ + h * D_ + cc * 8] = v;
    }
}

// ---------------------------------------------------------------------------
extern "C" void kernel_launch(void* const* d_in, const int* in_sizes, int n_in,
                              void* d_out, int out_size, void* d_ws, size_t ws_size,
                              hipStream_t stream) {
    const float* x    = (const float*)d_in[0];
    const float* y    = (const float*)d_in[1];
    const void*  mask = d_in[2];
    const float* wq   = (const float*)d_in[3];
    const float* wk   = (const float*)d_in[4];
    const float* wo   = (const float*)d_in[5];

    // ws layout (bytes):
    //   [0,        16777216)  xT bf16   -> later ET bf16
    //   [16777216, 33554432)  yT bf16   -> later Kb bf16
    //   [33554432, 50331648)  Ka bf16
    //   [50331648, 50855936)  wq bf16
    //   [50855936, 51380224)  wk bf16
    //   [51380224, 51904512)  wo bf16
    //   [51904512, 54001664)  maskBits u32
    //   [54001664, 54067200)  nel f32
    //   [54067200, ...)       flag int
    char* wsb = (char*)d_ws;
    ushort_t* xT    = (ushort_t*)(wsb);
    ushort_t* yT    = (ushort_t*)(wsb + 16777216);
    ushort_t* Ka    = (ushort_t*)(wsb + 33554432);
    ushort_t* wqb   = (ushort_t*)(wsb + 50331648);
    ushort_t* wkb   = (ushort_t*)(wsb + 50855936);
    ushort_t* wob   = (ushort_t*)(wsb + 51380224);
    uint_t*   mbits = (uint_t*)(wsb + 51904512);
    float*    nel   = (float*)(wsb + 54001664);
    int*      flag  = (int*)(wsb + 54067200);
    ushort_t* ET    = xT;                 // alias: xT dead after Q-GEMM
    ushort_t* Kb    = yT;                 // alias: yT dead after K-GEMM
    ushort_t* QT    = (ushort_t*)d_out;   // QT[b][x][u] bf16 lives in d_out

    detect_kernel<<<1, 256, 0, stream>>>((const uint_t*)mask, flag);
    nelmask_kernel<<<(B_ * LX_) / 4, 256, 0, stream>>>(mask, flag, nel, mbits);
    castw_kernel<<<dim3(U_ * U_ / 1024, 3), 256, 0, stream>>>(wq, wk, wo, wqb, wkb, wob);
    castT_kernel<<<dim3(16, 8, 32), 256, 0, stream>>>(x, y, xT, yT);

    // QT[b][x][u] = xT[b] (M=1024) x wq (N=512)
    gemm_mfma<0><<<dim3(4, 8, B_), 256, 0, stream>>>(
        xT, (size_t)LX_ * U_, wqb, 0, (void*)QT, (size_t)LX_ * U_, U_);
    // Ka[b][u][y] = wk (M=512) x yT[b] (N=1024)
    gemm_mfma<0><<<dim3(8, 4, B_), 256, 0, stream>>>(
        wkb, 0, yT, (size_t)LY_ * U_, (void*)Ka, (size_t)U_ * LY_, LY_);
    ktranspose_kernel<<<dim3(LY_ / 64, H_, B_), 256, 0, stream>>>(Ka, Kb);
    attn_mfma<<<1024, 256, 0, stream>>>(QT, Ka, Kb, mbits, nel, ET);
    // out[b][u][x] fp32 = wo (M=512) x ET[b] (N=1024)
    gemm_mfma<1><<<dim3(8, 4, B_), 256, 0, stream>>>(
        wob, 0, ET, (size_t)LX_ * U_, d_out, (size_t)U_ * LX_, LX_);
}

// Round 3
// 283.854 us; speedup vs baseline: 1.3800x; 1.3800x over previous
//
#include <hip/hip_runtime.h>
#include <stdint.h>
#include <stddef.h>

#define B_  16
#define U_  512
#define LX_ 1024
#define LY_ 1024
#define H_  8
#define D_  64

typedef unsigned short ushort_t;
typedef unsigned int   uint_t;
typedef __bf16 v8bf  __attribute__((ext_vector_type(8)));
typedef float  v16f  __attribute__((ext_vector_type(16)));

__device__ __forceinline__ ushort_t bf16u(float f) {
    uint_t u = __float_as_uint(f);
    uint_t r = (u + 0x7FFFu + ((u >> 16) & 1u)) >> 16;
    return (ushort_t)r;
}
__device__ __forceinline__ float bfu2f(ushort_t u) {
    return __uint_as_float(((uint_t)u) << 16);
}
// RNE-pack two fp32 -> packed bf16x2 (low=f0) using v_perm_b32.
__device__ __forceinline__ uint_t pkbf16(float f0, float f1) {
    uint_t u0 = __float_as_uint(f0), u1 = __float_as_uint(f1);
    u0 = u0 + 0x7FFFu + ((u0 >> 16) & 1u);
    u1 = u1 + 0x7FFFu + ((u1 >> 16) & 1u);
    return __builtin_amdgcn_perm(u1, u0, 0x07060302u);
}
// async global->LDS, 16B/lane. LDS dest is wave-uniform base + lane*16, so
// swizzling must be applied to the GLOBAL source chunk, not the LDS address.
__device__ __forceinline__ void gload16(const void* g, void* l) {
    auto gp = (const __attribute__((address_space(1))) uint32_t*)(uintptr_t)g;
    auto lp = (__attribute__((address_space(3))) uint32_t*)(uintptr_t)l;
    __builtin_amdgcn_global_load_lds(gp, lp, 16, 0, 0);
}

// ---------------------------------------------------------------------------
// Detect mask element width: int32 (all first-1024 words <= 1) vs uint8.
// ---------------------------------------------------------------------------
__global__ void detect_kernel(const uint_t* __restrict__ mask, int* __restrict__ flag) {
    __shared__ int s;
    if (threadIdx.x == 0) s = 0;
    __syncthreads();
    int c = 0;
    for (int i = threadIdx.x; i < 1024; i += 256) c += (mask[i] <= 1u) ? 1 : 0;
    atomicAdd(&s, c);
    __syncthreads();
    if (threadIdx.x == 0) *flag = (s >= 1000) ? 1 : 0;
}

// ---------------------------------------------------------------------------
// Single mask pass: maskBits (ballot) + n_el (popcount). One wave per row.
// ---------------------------------------------------------------------------
__global__ __launch_bounds__(256) void nelmask_kernel(const void* __restrict__ mask,
                                                      const int* __restrict__ flag,
                                                      float* __restrict__ nel,
                                                      uint_t* __restrict__ mb) {
    int row  = blockIdx.x * 4 + (threadIdx.x >> 6);   // b*1024 + x
    int lane = threadIdx.x & 63;
    const int isInt = *flag;
    const uint8_t* m8  = (const uint8_t*)mask + (size_t)row * LY_;
    const int*     m32 = (const int*)mask + (size_t)row * LY_;
    int cnt = 0;
    for (int yg = 0; yg < LY_ / 64; ++yg) {
        int y = yg * 64 + lane;
        bool p = isInt ? (m32[y] != 0) : (m8[y] != 0);
        unsigned long long bal = __ballot(p);
        if (lane == 0) {
            mb[(size_t)row * 32 + yg * 2]     = (uint_t)bal;
            mb[(size_t)row * 32 + yg * 2 + 1] = (uint_t)(bal >> 32);
            cnt += __popcll(bal);
        }
    }
    if (lane == 0) nel[row] = (float)(cnt > 0 ? cnt : 1);
}

// ---------------------------------------------------------------------------
// All three 512x512 weights -> bf16 in one dispatch (blockIdx.y selects).
// ---------------------------------------------------------------------------
__global__ __launch_bounds__(256) void castw_kernel(const float* __restrict__ w0,
                                                    const float* __restrict__ w1,
                                                    const float* __restrict__ w2,
                                                    ushort_t* __restrict__ o0,
                                                    ushort_t* __restrict__ o1,
                                                    ushort_t* __restrict__ o2) {
    const float* s = blockIdx.y == 0 ? w0 : (blockIdx.y == 1 ? w1 : w2);
    ushort_t*    d = blockIdx.y == 0 ? o0 : (blockIdx.y == 1 ? o1 : o2);
    int i = (blockIdx.x * 256 + threadIdx.x) * 4;
    float4 v = *(const float4*)&s[i];
    ushort4 p;
    p.x = bf16u(v.x); p.y = bf16u(v.y); p.z = bf16u(v.z); p.w = bf16u(v.w);
    *(ushort4*)&d[i] = p;
}

// ---------------------------------------------------------------------------
// x and y [b][u][l] fp32 -> [b][l][u] bf16, 64x64 LDS tiles. z = b + 16*sel.
// ---------------------------------------------------------------------------
__global__ __launch_bounds__(256) void castT_kernel(const float* __restrict__ X,
                                                    const float* __restrict__ Y,
                                                    ushort_t* __restrict__ XT,
                                                    ushort_t* __restrict__ YT) {
    const int l0 = blockIdx.x * 64;
    const int u0 = blockIdx.y * 64;
    const int b  = blockIdx.z & 15;
    const int sel = blockIdx.z >> 4;
    const float* S = sel ? Y : X;
    ushort_t*  Dst = sel ? YT : XT;
    __shared__ ushort_t T[64][72];
    const int tid = threadIdx.x;
    #pragma unroll
    for (int e = 0; e < 4; ++e) {
        int ci = e * 256 + tid;            // 0..1023 float4s
        int r = ci >> 4, c4 = (ci & 15) * 4;
        float4 v = *(const float4*)&S[((size_t)(b * U_ + u0 + r) << 10) + l0 + c4];
        T[r][c4 + 0] = bf16u(v.x); T[r][c4 + 1] = bf16u(v.y);
        T[r][c4 + 2] = bf16u(v.z); T[r][c4 + 3] = bf16u(v.w);
    }
    __syncthreads();
    #pragma unroll
    for (int e = 0; e < 2; ++e) {
        int ci = e * 256 + tid;            // 0..511 chunks of 8
        int lr = ci >> 3, cc = ci & 7;
        ushort_t tmp[8];
        #pragma unroll
        for (int j = 0; j < 8; ++j) tmp[j] = T[cc * 8 + j][lr];
        *(uint4*)&Dst[((size_t)((b << 10) + l0 + lr)) * U_ + u0 + cc * 8] = *(uint4*)tmp;
    }
}

// ---------------------------------------------------------------------------
// Generalized bf16 MFMA GEMM: Out[b][m][n] = sum_k A_b[m][k] * B_b[n][k]
// K = 512 (= lda = ldb). 128x128 tile, BK=64, gload16 staging, src-xor swizzle.
// aStr/bStr: per-batch element strides (0 = shared). Out: oStr*b + m*ldOut + n.
// ---------------------------------------------------------------------------
template <int OUTF32>
__global__ __launch_bounds__(256) void gemm_mfma(const ushort_t* __restrict__ A, size_t aStr,
                                                 const ushort_t* __restrict__ Bm, size_t bStr,
                                                 void* __restrict__ Out, size_t oStr, int ldOut) {
    const int n0 = blockIdx.x * 128;
    const int m0 = blockIdx.y * 128;
    const int b  = blockIdx.z;
    __shared__ __align__(16) ushort_t As[128 * 64];
    __shared__ __align__(16) ushort_t Bs[128 * 64];
    const int tid = threadIdx.x;
    const ushort_t* Ab = A + aStr * b;
    const ushort_t* Bb = Bm + bStr * b;

    const int w = tid >> 6, lane = tid & 63, lo = lane & 31, hi = lane >> 5;
    const int wm = (w >> 1) * 64, wn = (w & 1) * 64;

    v16f acc00, acc01, acc10, acc11;
    #pragma unroll
    for (int i = 0; i < 16; ++i) { acc00[i] = 0.f; acc01[i] = 0.f; acc10[i] = 0.f; acc11[i] = 0.f; }

    for (int kk = 0; kk < 8; ++kk) {
        const int k0 = kk * 64;
        #pragma unroll
        for (int e = 0; e < 4; ++e) {
            int ci = e * 256 + tid;          // 0..1023 16B chunks
            int r = ci >> 3, c = ci & 7;
            int g = (c ^ (r & 7)) << 3;      // swizzle on SOURCE chunk
            gload16(&Ab[(size_t)(m0 + r) * U_ + k0 + g], &As[ci * 8]);
            gload16(&Bb[(size_t)(n0 + r) * U_ + k0 + g], &Bs[ci * 8]);
        }
        __syncthreads();
        #pragma unroll
        for (int ks = 0; ks < 4; ++ks) {
            int ch = ks * 2 + hi;
            int rA0 = wm + lo, rA1 = wm + 32 + lo;
            int rB0 = wn + lo, rB1 = wn + 32 + lo;
            v8bf a0 = *(v8bf*)&As[rA0 * 64 + ((ch ^ (rA0 & 7)) << 3)];
            v8bf a1 = *(v8bf*)&As[rA1 * 64 + ((ch ^ (rA1 & 7)) << 3)];
            v8bf b0 = *(v8bf*)&Bs[rB0 * 64 + ((ch ^ (rB0 & 7)) << 3)];
            v8bf b1 = *(v8bf*)&Bs[rB1 * 64 + ((ch ^ (rB1 & 7)) << 3)];
            acc00 = __builtin_amdgcn_mfma_f32_32x32x16_bf16(a0, b0, acc00, 0, 0, 0);
            acc01 = __builtin_amdgcn_mfma_f32_32x32x16_bf16(a0, b1, acc01, 0, 0, 0);
            acc10 = __builtin_amdgcn_mfma_f32_32x32x16_bf16(a1, b0, acc10, 0, 0, 0);
            acc11 = __builtin_amdgcn_mfma_f32_32x32x16_bf16(a1, b1, acc11, 0, 0, 0);
        }
        __syncthreads();
    }

    #pragma unroll
    for (int mi = 0; mi < 2; ++mi) {
        #pragma unroll
        for (int nj = 0; nj < 2; ++nj) {
            v16f c = mi ? (nj ? acc11 : acc10) : (nj ? acc01 : acc00);
            int n = n0 + wn + nj * 32 + lo;
            #pragma unroll
            for (int r = 0; r < 16; ++r) {
                int m = m0 + wm + mi * 32 + (r & 3) + 8 * (r >> 2) + 4 * hi;
                size_t addr = oStr * b + (size_t)m * ldOut + n;
                if (OUTF32) ((float*)Out)[addr] = c[r];
                else        ((ushort_t*)Out)[addr] = bf16u(c[r]);
            }
        }
    }
}

// ---------------------------------------------------------------------------
// Ka[b][u=h*64+d][y] bf16 -> Kb[b][h][y][d] bf16 (64x64 LDS transpose)
// ---------------------------------------------------------------------------
__global__ __launch_bounds__(256) void ktranspose_kernel(const ushort_t* __restrict__ Ka,
                                                         ushort_t* __restrict__ Kb) {
    const int y0 = blockIdx.x * 64;
    const int h  = blockIdx.y;
    const int b  = blockIdx.z;
    __shared__ ushort_t T[64][72];
    const int tid = threadIdx.x;

    #pragma unroll
    for (int e = 0; e < 2; ++e) {
        int idx = e * 256 + tid;
        int d = idx >> 3, c = idx & 7;
        uint4 v = *(const uint4*)&Ka[((size_t)(b * U_ + h * D_ + d) << 10) + y0 + c * 8];
        *(uint4*)&T[d][c * 8] = v;
    }
    __syncthreads();
    #pragma unroll
    for (int e = 0; e < 2; ++e) {
        int idx = e * 256 + tid;
        int yy = idx >> 3, dc = idx & 7;
        ushort_t tmp[8];
        #pragma unroll
        for (int j = 0; j < 8; ++j) tmp[j] = T[dc * 8 + j][yy];
        *(uint4*)&Kb[(((size_t)(b * H_ + h) << 10) + y0 + yy) * D_ + dc * 8] = *(uint4*)tmp;
    }
}

// ---------------------------------------------------------------------------
// Fused bf16-MFMA attention, 4-way x-split, in-register S->C handoff, 32 KB.
//
// Each wave owns ONE x-quarter (32 x-cols), full y, full d: acc = 2 x v16f
// (32 regs), qf = 4 x v8bf (16 regs), peak live ~100 regs -> fits the
// 4-waves/SIMD budget (128) WITHOUT spilling (R2's failure was capping a
// ~170-reg live set at 128 -> scratch explosion: FETCH 470MB).  LDS is the
// 32KB double-buffered K tiles only -> 4 blocks/CU by LDS and VGPR: all
// 1024 blocks co-resident, single dispatch phase.  Because a wave owns all
// y for its x-cols, partial-C cross-wave reduction is gone: the epilogue
// finalizes E per-wave straight into the dead K region (Et) and streams out.
// ---------------------------------------------------------------------------
typedef uint_t v2u __attribute__((ext_vector_type(2)));

// s: 16 f32 of one 32x32 S^T block (D-layout, cols = this lane's x). wbh:
// mask word for the block's 32 y's >> (hi*8).  fr[t]: B-operand fragment for
// k-step t (t=0: y_off 0..15, t=1: 16..31 relative to the block).
__device__ __forceinline__ void conv_sblock(const v16f& s, uint_t wbh, v8bf* fr) {
    uint_t pk[8];
    #pragma unroll
    for (int i = 0; i < 8; ++i) {
        float f0 = fmaxf(s[2 * i + 0], 0.f);
        float f1 = fmaxf(s[2 * i + 1], 0.f);
        uint_t r;
        asm("v_cvt_pk_bf16_f32 %0, %1, %2" : "=v"(r) : "v"(f0), "v"(f1));
        pk[i] = r;
    }
    #pragma unroll
    for (int t = 0; t < 2; ++t) {
        // swap(A,B): A'[32+i]=B[i], B'[i]=A[32+i]
        auto ra = __builtin_amdgcn_permlane32_swap(pk[4 * t + 0], pk[4 * t + 2], false, false);
        auto rb = __builtin_amdgcn_permlane32_swap(pk[4 * t + 1], pk[4 * t + 3], false, false);
        uint_t w0 = ra[0];   // j={0,1}:  y_off = t*16 + hi*8 + {0,1}
        uint_t w1 = rb[0];   // j={2,3}
        uint_t w2 = ra[1];   // j={4,5}
        uint_t w3 = rb[1];   // j={6,7}
        uint_t u0 = wbh >> (t * 16 + 0);
        uint_t u1 = wbh >> (t * 16 + 2);
        uint_t u2 = wbh >> (t * 16 + 4);
        uint_t u3 = wbh >> (t * 16 + 6);
        w0 &= ((u0 & 1u) * 0xFFFFu) | ((u0 & 2u) * 0x7FFF8000u);
        w1 &= ((u1 & 1u) * 0xFFFFu) | ((u1 & 2u) * 0x7FFF8000u);
        w2 &= ((u2 & 1u) * 0xFFFFu) | ((u2 & 2u) * 0x7FFF8000u);
        w3 &= ((u3 & 1u) * 0xFFFFu) | ((u3 & 2u) * 0x7FFF8000u);
        union { uint_t u[4]; v8bf b; } cv;
        cv.u[0] = w0; cv.u[1] = w1; cv.u[2] = w2; cv.u[3] = w3;
        fr[t] = cv.b;
    }
}

__global__ __launch_bounds__(256, 4) void attn_mfma(const ushort_t* __restrict__ QTg,
                                                    const ushort_t* __restrict__ Ka_g,
                                                    const ushort_t* __restrict__ Kb_g,
                                                    const uint_t* __restrict__ mbits,
                                                    const float* __restrict__ nel,
                                                    ushort_t* __restrict__ ETg) {
    const int tid = threadIdx.x;
    const int id  = blockIdx.x;
    const int bh  = id & 127;          // same-bh blocks -> same XCD (id%8 heuristic)
    const int x0g = (id >> 7) * 128;
    const int b = bh >> 3, h = bh & 7;

    // 32 KB: KB dbuf [0,16KB) | KA dbuf [16KB,32KB).  Reused post-loop as Et.
    __shared__ __align__(16) ushort_t SM[4 * 4096];

    const int w    = tid >> 6;         // x-quarter index 0..3
    const int lane = tid & 63;
    const int lo   = lane & 31;
    const int hi   = lane >> 5;
    const int xq   = w * 32;           // x-quarter base within the 128-x tile

    const ushort_t* KaBase = Ka_g + ((size_t)(b * U_ + h * D_)) * LY_;
    const ushort_t* KbBase = Kb_g + ((size_t)(b * H_ + h)) * LY_ * D_;
    const int bx = b * LX_ + x0g;
    const int xg = bx + xq + lo;       // this lane's global x row

    // ---- stage first K tile into buffer 0 ----
    #pragma unroll
    for (int e = 0; e < 2; ++e) {
        int ci = e * 256 + tid;
        int r = ci >> 3, c = ci & 7;
        int g8 = (c ^ (r & 7)) << 3;
        gload16(&KbBase[(size_t)r * D_ + g8], &SM[ci * 8]);
        gload16(&KaBase[(size_t)r * LY_ + g8], &SM[8192 + ci * 8]);
    }

    // ---- Q B-fragments straight from global (loop-invariant, 16 VGPR) ----
    v8bf qf[4];
    {
        const ushort_t* q0 = QTg + (size_t)xg * U_ + h * D_;
        #pragma unroll
        for (int kt = 0; kt < 4; ++kt) qf[kt] = *(const v8bf*)&q0[(kt * 2 + hi) * 8];
    }

    // full-C accumulators for this x-quarter: acc0 = d 0..31, acc1 = d 32..63
    v16f acc0, acc1;
    #pragma unroll
    for (int i = 0; i < 16; ++i) { acc0[i] = 0.f; acc1[i] = 0.f; }

    __syncthreads();   // first tile staged (drains gload_lds)

    for (int tt = 0; tt < 16; ++tt) {
        ushort_t* KBc = SM + (tt & 1) * 4096;
        ushort_t* KAc = SM + 8192 + (tt & 1) * 4096;

        // prefetch next tile into other buffer; drained by end-of-tile barrier
        if (tt < 15) {
            ushort_t* KBn = SM + ((tt + 1) & 1) * 4096;
            ushort_t* KAn = SM + 8192 + ((tt + 1) & 1) * 4096;
            const int yn = tt * 64 + 64;
            #pragma unroll
            for (int e = 0; e < 2; ++e) {
                int ci = e * 256 + tid;
                int r = ci >> 3, c = ci & 7;
                int g8 = (c ^ (r & 7)) << 3;
                gload16(&KbBase[(size_t)(yn + r) * D_ + g8], &KBn[ci * 8]);
                gload16(&KaBase[(size_t)r * LY_ + yn + g8], &KAn[ci * 8]);
            }
        }
        // both 32-y mask words for this lane's x row, one 8B load
        v2u wb = *(const v2u*)&mbits[(size_t)xg * 32 + tt * 2];

        // ---- S-phase, y-block 0 (y0..y0+31): S^T = Kb * Q^T ----
        v8bf fr0[2], fr1[2];
        {
            v16f s;
            #pragma unroll
            for (int i = 0; i < 16; ++i) s[i] = 0.f;
            #pragma unroll
            for (int kt = 0; kt < 4; ++kt) {
                int ch = kt * 2 + hi;
                v8bf a = *(v8bf*)&KBc[lo * 64 + ((ch ^ (lo & 7)) << 3)];
                s = __builtin_amdgcn_mfma_f32_32x32x16_bf16(a, qf[kt], s, 0, 0, 0);
            }
            conv_sblock(s, wb[0] >> (hi * 8), fr0);
        }
        // ---- S-phase, y-block 1 (y0+32..y0+63) ----
        {
            v16f s;
            #pragma unroll
            for (int i = 0; i < 16; ++i) s[i] = 0.f;
            #pragma unroll
            for (int kt = 0; kt < 4; ++kt) {
                int ch = kt * 2 + hi;
                v8bf a = *(v8bf*)&KBc[(32 + lo) * 64 + ((ch ^ ((32 + lo) & 7)) << 3)];
                s = __builtin_amdgcn_mfma_f32_32x32x16_bf16(a, qf[kt], s, 0, 0, 0);
            }
            conv_sblock(s, wb[1] >> (hi * 8), fr1);
        }

        // ---- C-phase: C[d][x-quarter] += Ka * S over all 64 y ----
        #pragma unroll
        for (int kt = 0; kt < 4; ++kt) {
            int ch = kt * 2 + hi;
            v8bf frk = (kt < 2) ? fr0[kt] : fr1[kt - 2];
            v8bf a0 = *(v8bf*)&KAc[lo * 64 + ((ch ^ (lo & 7)) << 3)];
            v8bf a1 = *(v8bf*)&KAc[(32 + lo) * 64 + ((ch ^ ((32 + lo) & 7)) << 3)];
            acc0 = __builtin_amdgcn_mfma_f32_32x32x16_bf16(a0, frk, acc0, 0, 0, 0);
            acc1 = __builtin_amdgcn_mfma_f32_32x32x16_bf16(a1, frk, acc1, 0, 0, 0);
        }
        __syncthreads();   // drains prefetch vmcnt + protects buffer swap
    }

    // ---- epilogue: E = 0.5*Q + C*(0.0625/nel) -> Et (dead K region) ----
    // Wave owns full C for its x-quarter; no cross-wave reduction needed.
    {
        ushort_t* Et = SM;
        const int xl = xq + lo;
        float invn = 0.0625f / nel[xg];
        const ushort_t* qg = QTg + (size_t)xg * U_ + h * D_ + 4 * hi;
        #pragma unroll
        for (int half = 0; half < 2; ++half) {
            const v16f& c = half ? acc1 : acc0;
            #pragma unroll
            for (int q = 0; q < 4; ++q) {
                int d0 = half * 32 + q * 8 + 4 * hi;               // d0&7 == 4*hi
                ushort_t q4[4];
                *(uint2*)q4 = *(const uint2*)&qg[half * 32 + q * 8];
                ushort_t e4[4];
                e4[0] = bf16u(0.5f * bfu2f(q4[0]) + c[q * 4 + 0] * invn);
                e4[1] = bf16u(0.5f * bfu2f(q4[1]) + c[q * 4 + 1] * invn);
                e4[2] = bf16u(0.5f * bfu2f(q4[2]) + c[q * 4 + 2] * invn);
                e4[3] = bf16u(0.5f * bfu2f(q4[3]) + c[q * 4 + 3] * invn);
                int base = xl * 64 + ((((d0 >> 3) ^ (xl & 7)) << 3) | (4 * hi));
                *(uint2*)&Et[base] = *(uint2*)e4;
            }
        }
    }
    __syncthreads();
    // ---- write ET[b][x][h*64+d] coalesced (un-swizzle on read) ----
    #pragma unroll
    for (int e = 0; e < 4; ++e) {
        int idx = e * 256 + tid;
        int row = idx >> 3, cc = idx & 7;
        uint4 v = *(const uint4*)&SM[row * 64 + ((cc ^ (row & 7)) << 3)];
        *(uint4*)&ETg[((size_t)(bx + row)) * U_ + h * D_ + cc * 8] = v;
    }
}

// ---------------------------------------------------------------------------
extern "C" void kernel_launch(void* const* d_in, const int* in_sizes, int n_in,
                              void* d_out, int out_size, void* d_ws, size_t ws_size,
                              hipStream_t stream) {
    const float* x    = (const float*)d_in[0];
    const float* y    = (const float*)d_in[1];
    const void*  mask = d_in[2];
    const float* wq   = (const float*)d_in[3];
    const float* wk   = (const float*)d_in[4];
    const float* wo   = (const float*)d_in[5];

    // ws layout (bytes):
    //   [0,        16777216)  xT bf16   -> later ET bf16
    //   [16777216, 33554432)  yT bf16   -> later Kb bf16
    //   [33554432, 50331648)  Ka bf16
    //   [50331648, 50855936)  wq bf16
    //   [50855936, 51380224)  wk bf16
    //   [51380224, 51904512)  wo bf16
    //   [51904512, 54001664)  maskBits u32
    //   [54001664, 54067200)  nel f32
    //   [54067200, ...)       flag int
    char* wsb = (char*)d_ws;
    ushort_t* xT    = (ushort_t*)(wsb);
    ushort_t* yT    = (ushort_t*)(wsb + 16777216);
    ushort_t* Ka    = (ushort_t*)(wsb + 33554432);
    ushort_t* wqb   = (ushort_t*)(wsb + 50331648);
    ushort_t* wkb   = (ushort_t*)(wsb + 50855936);
    ushort_t* wob   = (ushort_t*)(wsb + 51380224);
    uint_t*   mbits = (uint_t*)(wsb + 51904512);
    float*    nel   = (float*)(wsb + 54001664);
    int*      flag  = (int*)(wsb + 54067200);
    ushort_t* ET    = xT;                 // alias: xT dead after Q-GEMM
    ushort_t* Kb    = yT;                 // alias: yT dead after K-GEMM
    ushort_t* QT    = (ushort_t*)d_out;   // QT[b][x][u] bf16 lives in d_out

    detect_kernel<<<1, 256, 0, stream>>>((const uint_t*)mask, flag);
    nelmask_kernel<<<(B_ * LX_) / 4, 256, 0, stream>>>(mask, flag, nel, mbits);
    castw_kernel<<<dim3(U_ * U_ / 1024, 3), 256, 0, stream>>>(wq, wk, wo, wqb, wkb, wob);
    castT_kernel<<<dim3(16, 8, 32), 256, 0, stream>>>(x, y, xT, yT);

    // QT[b][x][u] = xT[b] (M=1024) x wq (N=512)
    gemm_mfma<0><<<dim3(4, 8, B_), 256, 0, stream>>>(
        xT, (size_t)LX_ * U_, wqb, 0, (void*)QT, (size_t)LX_ * U_, U_);
    // Ka[b][u][y] = wk (M=512) x yT[b] (N=1024)
    gemm_mfma<0><<<dim3(8, 4, B_), 256, 0, stream>>>(
        wkb, 0, yT, (size_t)LY_ * U_, (void*)Ka, (size_t)U_ * LY_, LY_);
    ktranspose_kernel<<<dim3(LY_ / 64, H_, B_), 256, 0, stream>>>(Ka, Kb);
    attn_mfma<<<1024, 256, 0, stream>>>(QT, Ka, Kb, mbits, nel, ET);
    // out[b][u][x] fp32 = wo (M=512) x ET[b] (N=1024)
    gemm_mfma<1><<<dim3(8, 4, B_), 256, 0, stream>>>(
        wob, 0, ET, (size_t)LX_ * U_, d_out, (size_t)U_ * LX_, LX_);
}